// Round 8
// baseline (295.496 us; speedup 1.0000x reference)
//
#include <hip/hip_runtime.h>
#include <hip/hip_bf16.h>
#include <stdint.h>

#define S_LEN   4096
#define D_MODEL 1024
#define NHEAD   16
#define DK      64

typedef __attribute__((ext_vector_type(8))) __bf16 bf16x8;
typedef __attribute__((ext_vector_type(4))) float  f32x4;
using bf16 = __hip_bfloat16;

#define LOG2E     1.44269504f
#define FREQ_C    0.41524101186092028f   // log2(10000)/32

__device__ __forceinline__ void load_lds16(const bf16* g, bf16* l) {
    __builtin_amdgcn_global_load_lds(
        (const __attribute__((address_space(1))) void*)g,
        (__attribute__((address_space(3))) void*)l, 16, 0, 0);
}

// ---------------- fused fp32 -> bf16 convert (x + 4 weights), 4 elems/thread ----------------
__global__ void cvt_all(const float* __restrict__ x,
                        const float* __restrict__ w0, const float* __restrict__ w1,
                        const float* __restrict__ w2, const float* __restrict__ w3,
                        bf16* __restrict__ xb,
                        bf16* __restrict__ b0, bf16* __restrict__ b1,
                        bf16* __restrict__ b2, bf16* __restrict__ b3)
{
    size_t i4 = ((size_t)blockIdx.x * 256 + threadIdx.x) * 4;
    const float* s; bf16* d; size_t off;
    const size_t NX = (size_t)S_LEN * D_MODEL;         // 4M
    const size_t NW = (size_t)D_MODEL * D_MODEL;       // 1M
    if (i4 < NX) { s = x; d = xb; off = i4; }
    else {
        size_t j = i4 - NX;
        int sel = (int)(j >> 20);
        off = j & (NW - 1);
        s = sel == 0 ? w0 : sel == 1 ? w1 : sel == 2 ? w2 : w3;
        d = sel == 0 ? b0 : sel == 1 ? b1 : sel == 2 ? b2 : b3;
    }
    float4 v = *(const float4*)&s[off];
    bf16 t[4] __attribute__((aligned(8)));
    t[0] = __float2bfloat16(v.x); t[1] = __float2bfloat16(v.y);
    t[2] = __float2bfloat16(v.z); t[3] = __float2bfloat16(v.w);
    *(uint64_t*)&d[off] = *(const uint64_t*)t;
}

// ---------------- QKV GEMM with fused RoPE ----------------
// z = 0 -> Qb (bf16, rope'd, scale 0.125*log2e folded)
// z = 1 -> Kb (bf16, rope'd)
// z = 2 -> VtG (bf16, transposed [D][S])
__global__ __launch_bounds__(256) void qkv_gemm(
    const bf16* __restrict__ Xb,
    const bf16* __restrict__ Wq, const bf16* __restrict__ Wk, const bf16* __restrict__ Wv,
    const int* __restrict__ pos,
    bf16* __restrict__ Qb, bf16* __restrict__ Kb, bf16* __restrict__ VtG)
{
    const int K = D_MODEL, N = D_MODEL;
    int z = blockIdx.z;
    const bf16* B = (z == 0) ? Wq : (z == 1) ? Wk : Wv;

    __shared__ __align__(16) bf16 As[2][128 * 32];
    __shared__ __align__(16) bf16 Bs[2][128 * 32];
    __shared__ __align__(16) bf16 Ts[4][64 * 24];   // per-wave V-transpose strip

    int row0 = blockIdx.y * 128;
    int col0 = blockIdx.x * 128;
    int tid  = threadIdx.x;
    int wv   = tid >> 6, lane = tid & 63;
    int m16  = lane & 15, quad = lane >> 4;
    int wr   = (wv >> 1) * 64, wc = (wv & 1) * 64;
    int l4   = lane >> 2, l3 = (lane & 3) * 8;

    const bf16* ga_base = Xb + (size_t)(row0 + wv * 16 + l4) * K + l3;
    const bf16* gb_base = B  + (size_t)(col0 + wv * 16 + l4) * K + l3;

    auto stage = [&](int k0, int buf) {
        load_lds16(ga_base + k0,            &As[buf][wv * 512]);
        load_lds16(ga_base + k0 + 64 * K,   &As[buf][2048 + wv * 512]);
        load_lds16(gb_base + k0,            &Bs[buf][wv * 512]);
        load_lds16(gb_base + k0 + 64 * K,   &Bs[buf][2048 + wv * 512]);
    };

    f32x4 acc[4][4];
    #pragma unroll
    for (int i = 0; i < 4; i++)
        #pragma unroll
        for (int j = 0; j < 4; j++) acc[i][j] = (f32x4){0.f, 0.f, 0.f, 0.f};

    stage(0, 0);
    for (int k0 = 0; k0 < K; k0 += 32) {
        __syncthreads();
        int buf = (k0 >> 5) & 1;
        if (k0 + 32 < K) stage(k0 + 32, buf ^ 1);
        bf16x8 a[4], b[4];
        #pragma unroll
        for (int mi = 0; mi < 4; mi++) a[mi] = *(const bf16x8*)&As[buf][(wr + mi * 16 + m16) * 32 + quad * 8];
        #pragma unroll
        for (int ni = 0; ni < 4; ni++) b[ni] = *(const bf16x8*)&Bs[buf][(wc + ni * 16 + m16) * 32 + quad * 8];
        #pragma unroll
        for (int mi = 0; mi < 4; mi++)
            #pragma unroll
            for (int ni = 0; ni < 4; ni++)
                acc[mi][ni] = __builtin_amdgcn_mfma_f32_16x16x32_bf16(a[mi], b[ni], acc[mi][ni], 0, 0, 0);
    }

    if (z < 2) {
        // fused RoPE epilogue. C/D layout: col = wc+ni*16+m16, row = wr+mi*16+quad*4+r.
        bf16* O = (z == 0) ? Qb : Kb;
        const float qscale = (z == 0) ? 0.125f * LOG2E : 1.0f;
        const bool odd = (m16 & 1);
        float invf[4];
        #pragma unroll
        for (int ni = 0; ni < 4; ni++) {
            int hd = (wc + ni * 16 + m16) & 63;
            invf[ni] = exp2f(-(float)(hd >> 1) * FREQ_C);
        }
        #pragma unroll
        for (int mi = 0; mi < 4; mi++) {
            #pragma unroll
            for (int r = 0; r < 4; r++) {
                int gr = row0 + wr + mi * 16 + quad * 4 + r;
                float p = (float)pos[gr];
                #pragma unroll
                for (int ni = 0; ni < 4; ni++) {
                    float own = acc[mi][ni][r];
                    float other = __shfl_xor(own, 1);
                    float sn, cs;
                    __sincosf(p * invf[ni], &sn, &cs);
                    float rot = odd ? (other * sn + own * cs) : (own * cs - other * sn);
                    int gc = col0 + wc + ni * 16 + m16;
                    O[(size_t)gr * N + gc] = __float2bfloat16(rot * qscale);
                }
            }
        }
    } else {
        // per-wave transpose through LDS, then coalesced 16B stores to VtG[gc][gr]
        #pragma unroll
        for (int mi = 0; mi < 4; mi++) {
            #pragma unroll
            for (int nt = 0; nt < 4; nt++) {
                bf16 t4[4] __attribute__((aligned(8)));
                #pragma unroll
                for (int r = 0; r < 4; r++) t4[r] = __float2bfloat16(acc[mi][nt][r]);
                *(uint64_t*)&Ts[wv][(nt * 16 + m16) * 24 + quad * 4] = *(const uint64_t*)t4;
            }
            #pragma unroll
            for (int rep = 0; rep < 2; rep++) {
                int c  = (lane >> 1) + rep * 32;
                int r8 = lane & 1;
                bf16x8 val = *(const bf16x8*)&Ts[wv][c * 24 + r8 * 8];
                int gc = col0 + wc + c;
                int gr = row0 + wr + mi * 16 + r8 * 8;
                *(bf16x8*)&VtG[(size_t)gc * S_LEN + gr] = val;
            }
        }
    }
}

// ---------------- Output GEMM: out = Attn(bf16) * Wo^T -> fp32, 64x128 tiles ----------------
__global__ __launch_bounds__(256) void out_gemm(
    const bf16* __restrict__ A_, const bf16* __restrict__ B,
    float* __restrict__ C)
{
    const int K = D_MODEL, N = D_MODEL;
    __shared__ __align__(16) bf16 As[2][64 * 32];
    __shared__ __align__(16) bf16 Bs[2][128 * 32];

    int row0 = blockIdx.y * 64;
    int col0 = blockIdx.x * 128;
    int tid  = threadIdx.x;
    int wv   = tid >> 6, lane = tid & 63;
    int m16  = lane & 15, quad = lane >> 4;
    int wr   = (wv >> 1) * 32, wc = (wv & 1) * 64;
    int l4   = lane >> 2, l3 = (lane & 3) * 8;

    const bf16* ga_base = A_ + (size_t)(row0 + wv * 16 + l4) * K + l3;
    const bf16* gb_base = B  + (size_t)(col0 + wv * 16 + l4) * K + l3;

    auto stage = [&](int k0, int buf) {
        load_lds16(ga_base + k0,            &As[buf][wv * 512]);
        load_lds16(gb_base + k0,            &Bs[buf][wv * 512]);
        load_lds16(gb_base + k0 + 64 * K,   &Bs[buf][2048 + wv * 512]);
    };

    f32x4 acc[2][4];
    #pragma unroll
    for (int i = 0; i < 2; i++)
        #pragma unroll
        for (int j = 0; j < 4; j++) acc[i][j] = (f32x4){0.f, 0.f, 0.f, 0.f};

    stage(0, 0);
    for (int k0 = 0; k0 < K; k0 += 32) {
        __syncthreads();
        int buf = (k0 >> 5) & 1;
        if (k0 + 32 < K) stage(k0 + 32, buf ^ 1);
        bf16x8 a[2], b[4];
        #pragma unroll
        for (int mi = 0; mi < 2; mi++) a[mi] = *(const bf16x8*)&As[buf][(wr + mi * 16 + m16) * 32 + quad * 8];
        #pragma unroll
        for (int ni = 0; ni < 4; ni++) b[ni] = *(const bf16x8*)&Bs[buf][(wc + ni * 16 + m16) * 32 + quad * 8];
        #pragma unroll
        for (int mi = 0; mi < 2; mi++)
            #pragma unroll
            for (int ni = 0; ni < 4; ni++)
                acc[mi][ni] = __builtin_amdgcn_mfma_f32_16x16x32_bf16(a[mi], b[ni], acc[mi][ni], 0, 0, 0);
    }

    #pragma unroll
    for (int mi = 0; mi < 2; mi++)
        #pragma unroll
        for (int ni = 0; ni < 4; ni++)
            #pragma unroll
            for (int r = 0; r < 4; r++) {
                int gr = row0 + wr + mi * 16 + quad * 4 + r;
                int gc = col0 + wc + ni * 16 + m16;
                C[(size_t)gr * N + gc] = acc[mi][ni][r];
            }
}

// ---------------- Flash attention: transposed-S formulation, no P transpose ----------------
// 1024 blocks: h = bx&15, qt = 63-(bx>>4) (longest first). 64 q-rows, one head.
// S^T = K·Q^T via MFMA (A=K, B=Q): C/D gives col=q, row=key. The bf16(exp2(S^T))
// registers ARE the B-operand (P^T) for O^T = V^T·P^T at k=quad*4+j positions —
// implemented on the verified 16x16x32 MFMA by zero-padding k=quad*8+{4..7} on
// both operands. Row-sums l come from an extra MFMA with a ones-A-fragment
// (every lane ends with l for its own q=m16 -> no shuffles). No shift needed:
// softmax is scale-invariant and |s'|<=~40 is safe in fp32/bf16.
// Single-buffered K/V tiles (16.4 KB LDS), m97-style 2-barrier loop.
__global__ __launch_bounds__(256) void attn_kernel(
    const bf16* __restrict__ Qb, const bf16* __restrict__ Kb, const bf16* __restrict__ VtG,
    bf16* __restrict__ Attn)
{
    int bx  = blockIdx.x;
    int h   = bx & 15;
    int qt  = 63 - (bx >> 4);
    int tid = threadIdx.x;
    int wv  = tid >> 6, lane = tid & 63;
    int m16 = lane & 15, quad = lane >> 4;
    int l4  = lane >> 2, l3 = (lane & 3) * 8;
    int q0  = qt * 64;
    int hc  = h * DK;

    __shared__ __align__(16) bf16 smem[8192];      // 16 KB total
    bf16* KT0 = smem;                              // K tile, d 0..31:  [key][32]
    bf16* KT1 = smem + 2048;                       // K tile, d 32..63
    bf16* VT0 = smem + 4096;                       // V^T tile, key 0..31: [d][32]
    bf16* VT1 = smem + 6144;                       // V^T tile, key 32..63

    const bf16* kg = Kb  + (size_t)(wv * 16 + l4) * D_MODEL + hc + l3;
    const bf16* vg = VtG + (size_t)(hc + wv * 16 + l4) * S_LEN + l3;

    auto stage = [&](int kb) {
        size_t ko = (size_t)kb * 64;
        load_lds16(kg + ko * D_MODEL,        KT0 + wv * 512);
        load_lds16(kg + ko * D_MODEL + 32,   KT1 + wv * 512);
        load_lds16(vg + ko,                  VT0 + wv * 512);
        load_lds16(vg + ko + 32,             VT1 + wv * 512);
    };

    // Q fragments (B-operand; 0.125*log2e folded upstream)
    const int qrow = q0 + wv * 16 + m16;
    bf16x8 aq0 = *(const bf16x8*)&Qb[(size_t)qrow * D_MODEL + hc + quad * 8];
    bf16x8 aq1 = *(const bf16x8*)&Qb[(size_t)qrow * D_MODEL + hc + 32 + quad * 8];

    // ones A-fragment for l (lower K half only)
    const bf16 one_b = __float2bfloat16(1.0f);
    const bf16 zero_b = __float2bfloat16(0.0f);
    bf16x8 onesF;
    {
        bf16 t[8] __attribute__((aligned(16)));
        #pragma unroll
        for (int j = 0; j < 8; j++) t[j] = (j < 4) ? one_b : zero_b;
        onesF = *(const bf16x8*)t;
    }

    f32x4 o[4];     // O^T tiles: o[mt][r] = O^T[d=mt*16+quad*4+r][q=m16]
    f32x4 lacc;     // all regs = l[q=m16]
    #pragma unroll
    for (int t = 0; t < 4; t++) o[t] = (f32x4){0.f, 0.f, 0.f, 0.f};
    lacc = (f32x4){0.f, 0.f, 0.f, 0.f};

    const int q_g = q0 + wv * 16 + m16;

    for (int kb = 0; kb <= qt; ++kb) {
        __syncthreads();                 // all reads of previous tile done
        stage(kb);
        __syncthreads();                 // tile visible (vmcnt drained)

        // S^T = K Q^T : A = K-frag, B = Q-frag
        f32x4 sT[4];
        #pragma unroll
        for (int nt = 0; nt < 4; nt++) {
            bf16x8 ka = *(const bf16x8*)&KT0[(nt * 16 + m16) * 32 + quad * 8];
            bf16x8 kb_ = *(const bf16x8*)&KT1[(nt * 16 + m16) * 32 + quad * 8];
            f32x4 zv = (f32x4){0.f, 0.f, 0.f, 0.f};
            zv = __builtin_amdgcn_mfma_f32_16x16x32_bf16(ka, aq0, zv, 0, 0, 0);
            zv = __builtin_amdgcn_mfma_f32_16x16x32_bf16(kb_, aq1, zv, 0, 0, 0);
            sT[nt] = zv;
        }

        if (kb == qt) {   // causal mask on diagonal tile: key = kb*64+nt*16+quad*4+r
            int keyb = kb * 64 + quad * 4;
            #pragma unroll
            for (int nt = 0; nt < 4; nt++)
                #pragma unroll
                for (int r = 0; r < 4; r++)
                    if (keyb + nt * 16 + r > q_g) sT[nt][r] = -1e30f;
        }

        // P^T = exp2(S^T) as bf16, directly in B-fragment layout (k = quad*4+j)
        bf16x8 pf[4];
        #pragma unroll
        for (int nt = 0; nt < 4; nt++) {
            bf16 t[8] __attribute__((aligned(16)));
            #pragma unroll
            for (int r = 0; r < 4; r++) t[r] = __float2bfloat16(__builtin_amdgcn_exp2f(sT[nt][r]));
            #pragma unroll
            for (int r = 4; r < 8; r++) t[r] = zero_b;
            pf[nt] = *(const bf16x8*)t;
        }

        // l[q] += sum_key P^T[key][q]  (ones-A MFMA; all output rows identical)
        #pragma unroll
        for (int nt = 0; nt < 4; nt++)
            lacc = __builtin_amdgcn_mfma_f32_16x16x32_bf16(onesF, pf[nt], lacc, 0, 0, 0);

        // O^T += V^T P^T : A = V^T frag (keys quad*4+{0..3}, upper k zero)
        #pragma unroll
        for (int mt = 0; mt < 4; mt++) {
            #pragma unroll
            for (int nt = 0; nt < 4; nt++) {
                const bf16* vsrc = (nt < 2) ? VT0 : VT1;
                bf16 va[8] __attribute__((aligned(16)));
                *(uint64_t*)va = *(const uint64_t*)&vsrc[(mt * 16 + m16) * 32 + (nt & 1) * 16 + quad * 4];
                *(uint64_t*)(va + 4) = 0;
                o[mt] = __builtin_amdgcn_mfma_f32_16x16x32_bf16(*(const bf16x8*)va, pf[nt], o[mt], 0, 0, 0);
            }
        }
    }

    __syncthreads();   // done with K/V tiles; reuse smem for the O^T -> O transpose

    float inv = 1.0f / lacc[0];          // lacc[any] = l[q=m16]
    bf16* Ls = smem + wv * 1152;         // per-wave strip [16 q][72]
    #pragma unroll
    for (int mt = 0; mt < 4; mt++) {
        bf16 t[4] __attribute__((aligned(8)));
        #pragma unroll
        for (int r = 0; r < 4; r++) t[r] = __float2bfloat16(o[mt][r] * inv);
        *(uint64_t*)&Ls[m16 * 72 + mt * 16 + quad * 4] = *(const uint64_t*)t;
    }
    // wave-private round trip (in-order DS pipe within a wave; no barrier)
    {
        int q_ = lane >> 2, c_ = lane & 3;
        bf16x8 v0 = *(const bf16x8*)&Ls[q_ * 72 + c_ * 8];
        bf16x8 v1 = *(const bf16x8*)&Ls[q_ * 72 + 32 + c_ * 8];
        size_t rowg = (size_t)(q0 + wv * 16 + q_) * D_MODEL + hc;
        *(bf16x8*)&Attn[rowg + c_ * 8]      = v0;
        *(bf16x8*)&Attn[rowg + 32 + c_ * 8] = v1;
    }
}

extern "C" void kernel_launch(void* const* d_in, const int* in_sizes, int n_in,
                              void* d_out, int out_size, void* d_ws, size_t ws_size,
                              hipStream_t stream)
{
    const float* x  = (const float*)d_in[0];
    const int*   pos= (const int*)d_in[1];
    const float* Wq = (const float*)d_in[2];
    const float* Wk = (const float*)d_in[3];
    const float* Wv = (const float*)d_in[4];
    const float* Wo = (const float*)d_in[5];
    float* out = (float*)d_out;

    char* ws = (char*)d_ws;
    bf16*  xb   = (bf16*) (ws);                    // 8 MB
    bf16*  wqb  = (bf16*) (ws + ( 8ull << 20));    // 2 MB
    bf16*  wkb  = (bf16*) (ws + (10ull << 20));
    bf16*  wvb  = (bf16*) (ws + (12ull << 20));
    bf16*  wob  = (bf16*) (ws + (14ull << 20));
    bf16*  Qb   = (bf16*) (ws + (16ull << 20));    // 8 MB (rope'd, scaled)
    bf16*  Kb   = (bf16*) (ws + (24ull << 20));    // 8 MB (rope'd)
    bf16*  VtG  = (bf16*) (ws + (32ull << 20));    // 8 MB (V transposed [D][S])
    bf16*  Attn = (bf16*) (ws + (40ull << 20));    // 8 MB -> 48 MB total

    cvt_all<<<8192, 256, 0, stream>>>(x, Wq, Wk, Wv, Wo, xb, wqb, wkb, wvb, wob);

    qkv_gemm<<<dim3(8, 32, 3), 256, 0, stream>>>(xb, wqb, wkb, wvb, pos, Qb, Kb, VtG);

    attn_kernel<<<dim3(1024), 256, 0, stream>>>(Qb, Kb, VtG, Attn);

    out_gemm<<<dim3(8, 64), 256, 0, stream>>>(Attn, wob, out);
}